// Round 14
// baseline (24.914 us; speedup 1.0000x reference)
//
#include <hip/hip_runtime.h>

#define NQ 5
#define NL 6
#define NG 4
#define DIM 32
#define PATCH 16

typedef _Float16 half8 __attribute__((ext_vector_type(8)));
typedef float f32x4 __attribute__((ext_vector_type(4)));

// CZ-chain sign: flip amplitude i iff # adjacent set-bit pairs is odd.
__device__ __forceinline__ int flip_par(int i) {
    int p = i & (i >> 1) & 0xF;
    p ^= p >> 2; p ^= p >> 1;
    return p & 1;
}

// Single fused kernel. R14 = R13 with REGISTER-LIFETIME reordering only:
// relay + B-frag build moved BEFORE barrier (base[32] dies pre-barrier, no
// longer overlapping MhA/MlA -> peak live ~90 VGPR, no spill at the
// launch_bounds(256,4) cap of 128). B-wave sims first, does its relay after
// the barrier (lagging its own main loop slightly; no sync needed). Barrier 2
// dropped (lmMs dedicated since R13; relay/stage hazards are same-wave
// in-order DS). Everything else byte-identical to the R13 pass.
__global__ __launch_bounds__(256, 4) void qgen12(
        const float* __restrict__ x, const float* __restrict__ qp,
        float* __restrict__ out) {
    __shared__ __align__(16) f32x4 smem[4][512];   // 32 KB relay/stage
    __shared__ float lmMs[64 * DIM];               // 8 KB dedicated M

    const int t = threadIdx.x;
    const int wid = t >> 6, lane = t & 63;
    const int l15 = lane & 15, kg = lane >> 4;
    const int b0 = (blockIdx.x * 4 + wid) * 64;
    const bool bwave = (wid == ((blockIdx.x >> 8) & 3));  // SIMD-spread sim wave

    // ---- Phase A: per-lane trig + product state (verified R1-R13)
    const float RV = 0.07957747154594767f; // 0.5/(2*pi): v_sin/v_cos take revolutions
    float cn[NQ], sn[NQ];
    const float* xp = x + (size_t)(b0 + lane) * NQ;
    #pragma unroll
    for (int w = 0; w < NQ; ++w) {
        float h = xp[w] * RV;
        cn[w] = __builtin_amdgcn_cosf(h);
        sn[w] = __builtin_amdgcn_sinf(h);
    }
    float base[DIM];
    base[0] = cn[0]; base[1] = sn[0];
    #pragma unroll
    for (int w = 1; w < NQ; ++w) {
        #pragma unroll
        for (int j = (1 << w) - 1; j >= 0; --j) {
            float v = base[j];
            base[2*j + 1] = v * sn[w];
            base[2*j]     = v * cn[w];
        }
    }

    f32x4* relay = smem[wid];
    f32x4* stage = smem[wid];
    half8 BhF[4], BlF[4];

    // relay base -> B-frag order (wave-private slab; same-wave in-order DS).
    // base[] dies at the relay writes -> big live-range cut vs R13.
    auto build_bfrags = [&]() {
        #pragma unroll
        for (int q = 0; q < 8; ++q)
            relay[q * 64 + lane] = *(f32x4*)&base[q * 4];
        #pragma unroll
        for (int tb = 0; tb < 4; ++tb) {
            f32x4 r0 = relay[(kg*2 + 0) * 64 + tb*16 + l15];
            f32x4 r1 = relay[(kg*2 + 1) * 64 + tb*16 + l15];
            float b8[8] = {r0[0], r0[1], r0[2], r0[3], r1[0], r1[1], r1[2], r1[3]};
            half8 h, lo;
            #pragma unroll
            for (int e = 0; e < 8; ++e) {
                _Float16 hh = (_Float16)b8[e];
                h[e]  = hh;
                lo[e] = (_Float16)(b8[e] - (float)hh);
            }
            BhF[tb] = h; BlF[tb] = lo;
        }
    };

    if (!bwave) {
        build_bfrags();          // non-B waves progress while the sim runs
    } else {
        // ADJOINT basis sim -> M rows (math verified R12/R13):
        // row r of M = U'^T e_r; loop l=5..0 apply RY(-theta), sign after
        // each layer except l=0. lane -> (g=lane>>4, r=lane&15).
        const int g = lane >> 4;
        const int r = lane & 15;
        float st[DIM];
        #pragma unroll
        for (int i = 0; i < DIM; ++i) st[i] = (i == r) ? 1.0f : 0.0f;
        #pragma unroll
        for (int l = NL - 1; l >= 0; --l) {
            #pragma unroll
            for (int w = 0; w < NQ; ++w) {
                float h = qp[g*(NL*NQ) + l*NQ + w] * RV;
                float c = __builtin_amdgcn_cosf(h);
                float s = __builtin_amdgcn_sinf(h);
                const int bit = 4 - w, str = 1 << bit;
                #pragma unroll
                for (int p = 0; p < 16; ++p) {
                    int lo = ((p >> bit) << (bit + 1)) | (p & (str - 1));
                    int hi = lo + str;
                    float a0 = st[lo], a1 = st[hi];
                    st[lo] = c*a0 + s*a1;      // RY(-theta): transpose of fwd
                    st[hi] = c*a1 - s*a0;
                }
            }
            if (l != 0) {
                #pragma unroll
                for (int i = 0; i < DIM; ++i)
                    if (flip_par(i)) st[i] = -st[i];
            }
        }
        // swizzled write: bank (i+lane)&31 over 64 lanes = 2-way (free)
        #pragma unroll
        for (int i = 0; i < DIM; ++i)
            lmMs[(lane << 5) + ((i + lane) & 31)] = st[i];
    }
    __syncthreads();   // lmMs ready; the only barrier in the kernel

    if (bwave) build_bfrags();   // B-wave catches up (wave-private; no sync)

    // ---- A-fragments from lmMs (b32 reads, 2-way max), f16 hi/lo split
    half8 MhA[NG], MlA[NG];
    #pragma unroll
    for (int g = 0; g < NG; ++g) {
        const int row = g * PATCH + l15;
        float m8[8];
        #pragma unroll
        for (int e = 0; e < 8; ++e)
            m8[e] = lmMs[(row << 5) + ((kg*8 + e + row) & 31)];
        half8 h, lo;
        #pragma unroll
        for (int e = 0; e < 8; ++e) {
            _Float16 hh = (_Float16)m8[e];
            h[e]  = hh;
            lo[e] = (_Float16)(m8[e] - (float)hh);
        }
        MhA[g] = h; MlA[g] = lo;
    }

    // ---- main: FULLY UNROLLED tb x g (rule #20: all reg indices static).
    // Per tb: 4 gens x 3 MFMA -> scaled p into swizzled stage -> 4 x 1KB
    // contiguous store instrs (full lines). Verified R10/R11/R13.
    f32x4* ob4 = (f32x4*)(out + (size_t)b0 * 64);
    #pragma unroll
    for (int tb = 0; tb < 4; ++tb) {
        #pragma unroll
        for (int g = 0; g < NG; ++g) {
            f32x4 acc = {0.f, 0.f, 0.f, 0.f};
            acc = __builtin_amdgcn_mfma_f32_16x16x32_f16(MhA[g], BhF[tb], acc, 0, 0, 0);
            acc = __builtin_amdgcn_mfma_f32_16x16x32_f16(MlA[g], BhF[tb], acc, 0, 0, 0);
            acc = __builtin_amdgcn_mfma_f32_16x16x32_f16(MhA[g], BlF[tb], acc, 0, 0, 0);
            // D layout (m89-verified): reg r = slot kg*4+r, col l15 = batch.
            float p0 = acc[0]*acc[0], p1 = acc[1]*acc[1];
            float p2 = acc[2]*acc[2], p3 = acc[3]*acc[3];
            float mx = fmaxf(fmaxf(p0, p1), fmaxf(p2, p3));
            mx = fmaxf(mx, __shfl_xor(mx, 16, 64));   // combine the 4 kg lanes
            mx = fmaxf(mx, __shfl_xor(mx, 32, 64));
            float inv = __builtin_amdgcn_rcpf(mx);
            // swizzled slab: [batch l15][f4-slot (g*4+kg) ^ l15]
            f32x4 v = {p0*inv, p1*inv, p2*inv, p3*inv};
            stage[l15 * 16 + ((g*4 + kg) ^ l15)] = v;
        }
        // drain: 4 KB contiguous (batches tb*16..tb*16+15, full 256-B rows)
        #pragma unroll
        for (int j = 0; j < 4; ++j) {
            int f  = lane + 64 * j;      // f4 index within the tb region
            int br = f >> 4;             // local batch 0..15
            int sl = f & 15;             // f4 slot within the row
            ob4[tb * 256 + f] = stage[br * 16 + (sl ^ br)];
        }
    }
}

extern "C" void kernel_launch(void* const* d_in, const int* in_sizes, int n_in,
                              void* d_out, int out_size, void* d_ws, size_t ws_size,
                              hipStream_t stream) {
    const float* x  = (const float*)d_in[0];
    const float* qp = (const float*)d_in[1];
    float* out = (float*)d_out;
    const int B = in_sizes[0] / NQ;
    qgen12<<<B / 256, 256, 0, stream>>>(x, qp, out);
}

// Round 15
// 24.529 us; speedup vs baseline: 1.0157x; 1.0157x over previous
//
#include <hip/hip_runtime.h>

#define NQ 5
#define NL 6
#define NG 4
#define DIM 32
#define PATCH 16

typedef _Float16 half8 __attribute__((ext_vector_type(8)));
typedef float f32x4 __attribute__((ext_vector_type(4)));

// CZ-chain sign: flip amplitude i iff # adjacent set-bit pairs is odd.
__device__ __forceinline__ int flip_par(int i) {
    int p = i & (i >> 1) & 0xF;
    p ^= p >> 2; p ^= p >> 1;
    return p & 1;
}

// R15 = R14 with occupancy raised 4 -> 5 blocks/CU (TLP hypothesis):
//  * relay split into TWO 4 KB passes (pass1 = base[0..15] read by kg<2,
//    pass2 = base[16..31] read by kg>=2; same-wave in-order DS makes the
//    WAR between pass-1 reads and pass-2 writes safe) -> per-wave slab 4 KB
//    (union with the 4 KB stage), block LDS = 16 KB + 8 KB lmMs = 24 KB.
//  * __launch_bounds__(256, 5): VGPR cap 102 (est. live ~95 post-R14
//    lifetime ordering). 5 blocks/CU co-resident.
// All math/staging/drain byte-identical to the R13/R14 passes.
__global__ __launch_bounds__(256, 5) void qgen13(
        const float* __restrict__ x, const float* __restrict__ qp,
        float* __restrict__ out) {
    __shared__ __align__(16) f32x4 smem[4][256];   // 16 KB relay/stage (per-wave 4 KB)
    __shared__ float lmMs[64 * DIM];               // 8 KB dedicated M

    const int t = threadIdx.x;
    const int wid = t >> 6, lane = t & 63;
    const int l15 = lane & 15, kg = lane >> 4;
    const int b0 = (blockIdx.x * 4 + wid) * 64;
    const bool bwave = (wid == ((blockIdx.x >> 8) & 3));  // SIMD-spread sim wave

    // ---- Phase A: per-lane trig + product state (verified R1-R14)
    const float RV = 0.07957747154594767f; // 0.5/(2*pi): v_sin/v_cos take revolutions
    float cn[NQ], sn[NQ];
    const float* xp = x + (size_t)(b0 + lane) * NQ;
    #pragma unroll
    for (int w = 0; w < NQ; ++w) {
        float h = xp[w] * RV;
        cn[w] = __builtin_amdgcn_cosf(h);
        sn[w] = __builtin_amdgcn_sinf(h);
    }
    float base[DIM];
    base[0] = cn[0]; base[1] = sn[0];
    #pragma unroll
    for (int w = 1; w < NQ; ++w) {
        #pragma unroll
        for (int j = (1 << w) - 1; j >= 0; --j) {
            float v = base[j];
            base[2*j + 1] = v * sn[w];
            base[2*j]     = v * cn[w];
        }
    }

    f32x4* relay = smem[wid];
    f32x4* stage = smem[wid];
    half8 BhF[4], BlF[4];

    // Two-pass relay: slab holds 4 q-slabs at a time. Lane (kg,l15) needs
    // q = kg*2, kg*2+1: kg<2 -> pass 1 (q 0..3), kg>=2 -> pass 2 (q 4..7,
    // stored in slots 0..3). qa = slot of the lane's first q within its pass.
    const int qa = (kg & 1) * 2;
    auto build_bfrags = [&]() {
        #pragma unroll
        for (int q = 0; q < 4; ++q)                 // pass 1: base[0..15]
            relay[q * 64 + lane] = *(f32x4*)&base[q * 4];
        if (kg < 2) {
            #pragma unroll
            for (int tb = 0; tb < 4; ++tb) {
                f32x4 r0 = relay[(qa + 0) * 64 + tb*16 + l15];
                f32x4 r1 = relay[(qa + 1) * 64 + tb*16 + l15];
                float b8[8] = {r0[0],r0[1],r0[2],r0[3], r1[0],r1[1],r1[2],r1[3]};
                half8 h, lo;
                #pragma unroll
                for (int e = 0; e < 8; ++e) {
                    _Float16 hh = (_Float16)b8[e];
                    h[e] = hh; lo[e] = (_Float16)(b8[e] - (float)hh);
                }
                BhF[tb] = h; BlF[tb] = lo;
            }
        }
        #pragma unroll
        for (int q = 0; q < 4; ++q)                 // pass 2: base[16..31]
            relay[q * 64 + lane] = *(f32x4*)&base[16 + q * 4];
        if (kg >= 2) {
            #pragma unroll
            for (int tb = 0; tb < 4; ++tb) {
                f32x4 r0 = relay[(qa + 0) * 64 + tb*16 + l15];
                f32x4 r1 = relay[(qa + 1) * 64 + tb*16 + l15];
                float b8[8] = {r0[0],r0[1],r0[2],r0[3], r1[0],r1[1],r1[2],r1[3]};
                half8 h, lo;
                #pragma unroll
                for (int e = 0; e < 8; ++e) {
                    _Float16 hh = (_Float16)b8[e];
                    h[e] = hh; lo[e] = (_Float16)(b8[e] - (float)hh);
                }
                BhF[tb] = h; BlF[tb] = lo;
            }
        }
    };

    if (!bwave) {
        build_bfrags();          // non-B waves progress while the sim runs
    } else {
        // ADJOINT basis sim -> M rows (math verified R12-R14):
        // row r of M = U'^T e_r; loop l=5..0 apply RY(-theta), sign after
        // each layer except l=0. lane -> (g=lane>>4, r=lane&15).
        const int g = lane >> 4;
        const int r = lane & 15;
        float st[DIM];
        #pragma unroll
        for (int i = 0; i < DIM; ++i) st[i] = (i == r) ? 1.0f : 0.0f;
        #pragma unroll
        for (int l = NL - 1; l >= 0; --l) {
            #pragma unroll
            for (int w = 0; w < NQ; ++w) {
                float h = qp[g*(NL*NQ) + l*NQ + w] * RV;
                float c = __builtin_amdgcn_cosf(h);
                float s = __builtin_amdgcn_sinf(h);
                const int bit = 4 - w, str = 1 << bit;
                #pragma unroll
                for (int p = 0; p < 16; ++p) {
                    int lo = ((p >> bit) << (bit + 1)) | (p & (str - 1));
                    int hi = lo + str;
                    float a0 = st[lo], a1 = st[hi];
                    st[lo] = c*a0 + s*a1;      // RY(-theta): transpose of fwd
                    st[hi] = c*a1 - s*a0;
                }
            }
            if (l != 0) {
                #pragma unroll
                for (int i = 0; i < DIM; ++i)
                    if (flip_par(i)) st[i] = -st[i];
            }
        }
        // swizzled write: bank (i+lane)&31 over 64 lanes = 2-way (free)
        #pragma unroll
        for (int i = 0; i < DIM; ++i)
            lmMs[(lane << 5) + ((i + lane) & 31)] = st[i];
    }
    __syncthreads();   // lmMs ready; the only barrier in the kernel

    if (bwave) build_bfrags();   // B-wave catches up (wave-private; no sync)

    // ---- A-fragments from lmMs (b32 reads, 2-way max), f16 hi/lo split
    half8 MhA[NG], MlA[NG];
    #pragma unroll
    for (int g = 0; g < NG; ++g) {
        const int row = g * PATCH + l15;
        float m8[8];
        #pragma unroll
        for (int e = 0; e < 8; ++e)
            m8[e] = lmMs[(row << 5) + ((kg*8 + e + row) & 31)];
        half8 h, lo;
        #pragma unroll
        for (int e = 0; e < 8; ++e) {
            _Float16 hh = (_Float16)m8[e];
            h[e]  = hh;
            lo[e] = (_Float16)(m8[e] - (float)hh);
        }
        MhA[g] = h; MlA[g] = lo;
    }

    // ---- main: FULLY UNROLLED tb x g (rule #20: all reg indices static).
    // Per tb: 4 gens x 3 MFMA -> scaled p into swizzled stage -> 4 x 1KB
    // contiguous store instrs (full lines). Verified R10/R11/R13/R14.
    f32x4* ob4 = (f32x4*)(out + (size_t)b0 * 64);
    #pragma unroll
    for (int tb = 0; tb < 4; ++tb) {
        #pragma unroll
        for (int g = 0; g < NG; ++g) {
            f32x4 acc = {0.f, 0.f, 0.f, 0.f};
            acc = __builtin_amdgcn_mfma_f32_16x16x32_f16(MhA[g], BhF[tb], acc, 0, 0, 0);
            acc = __builtin_amdgcn_mfma_f32_16x16x32_f16(MlA[g], BhF[tb], acc, 0, 0, 0);
            acc = __builtin_amdgcn_mfma_f32_16x16x32_f16(MhA[g], BlF[tb], acc, 0, 0, 0);
            // D layout (m89-verified): reg r = slot kg*4+r, col l15 = batch.
            float p0 = acc[0]*acc[0], p1 = acc[1]*acc[1];
            float p2 = acc[2]*acc[2], p3 = acc[3]*acc[3];
            float mx = fmaxf(fmaxf(p0, p1), fmaxf(p2, p3));
            mx = fmaxf(mx, __shfl_xor(mx, 16, 64));   // combine the 4 kg lanes
            mx = fmaxf(mx, __shfl_xor(mx, 32, 64));
            float inv = __builtin_amdgcn_rcpf(mx);
            // swizzled slab: [batch l15][f4-slot (g*4+kg) ^ l15]
            f32x4 v = {p0*inv, p1*inv, p2*inv, p3*inv};
            stage[l15 * 16 + ((g*4 + kg) ^ l15)] = v;
        }
        // drain: 4 KB contiguous (batches tb*16..tb*16+15, full 256-B rows)
        #pragma unroll
        for (int j = 0; j < 4; ++j) {
            int f  = lane + 64 * j;      // f4 index within the tb region
            int br = f >> 4;             // local batch 0..15
            int sl = f & 15;             // f4 slot within the row
            ob4[tb * 256 + f] = stage[br * 16 + (sl ^ br)];
        }
    }
}

extern "C" void kernel_launch(void* const* d_in, const int* in_sizes, int n_in,
                              void* d_out, int out_size, void* d_ws, size_t ws_size,
                              hipStream_t stream) {
    const float* x  = (const float*)d_in[0];
    const float* qp = (const float*)d_in[1];
    float* out = (float*)d_out;
    const int B = in_sizes[0] / NQ;
    qgen13<<<B / 256, 256, 0, stream>>>(x, qp, out);
}

// Round 16
// 24.503 us; speedup vs baseline: 1.0167x; 1.0011x over previous
//
#include <hip/hip_runtime.h>

#define NQ 5
#define NL 6
#define NG 4
#define DIM 32
#define PATCH 16

typedef _Float16 half8 __attribute__((ext_vector_type(8)));
typedef float f32x4 __attribute__((ext_vector_type(4)));

// CZ-chain sign: flip amplitude i iff # adjacent set-bit pairs is odd.
__device__ __forceinline__ int flip_par(int i) {
    int p = i & (i >> 1) & 0xF;
    p ^= p >> 2; p ^= p >> 1;
    return p & 1;
}

// R16 = R14 (passed, 24.9) with ONE variable changed: the 16 drain stores are
// nontemporal (nt -> no L2 write-allocate for the write-once 64 MB output).
// Tests the last unfalsified hypothesis for the 24.6 µs plateau: L2 write-path
// throttling of the single-round store burst.
__global__ __launch_bounds__(256, 4) void qgen14(
        const float* __restrict__ x, const float* __restrict__ qp,
        float* __restrict__ out) {
    __shared__ __align__(16) f32x4 smem[4][512];   // 32 KB relay/stage
    __shared__ float lmMs[64 * DIM];               // 8 KB dedicated M

    const int t = threadIdx.x;
    const int wid = t >> 6, lane = t & 63;
    const int l15 = lane & 15, kg = lane >> 4;
    const int b0 = (blockIdx.x * 4 + wid) * 64;
    const bool bwave = (wid == ((blockIdx.x >> 8) & 3));  // SIMD-spread sim wave

    // ---- Phase A: per-lane trig + product state (verified R1-R15)
    const float RV = 0.07957747154594767f; // 0.5/(2*pi): v_sin/v_cos take revolutions
    float cn[NQ], sn[NQ];
    const float* xp = x + (size_t)(b0 + lane) * NQ;
    #pragma unroll
    for (int w = 0; w < NQ; ++w) {
        float h = xp[w] * RV;
        cn[w] = __builtin_amdgcn_cosf(h);
        sn[w] = __builtin_amdgcn_sinf(h);
    }
    float base[DIM];
    base[0] = cn[0]; base[1] = sn[0];
    #pragma unroll
    for (int w = 1; w < NQ; ++w) {
        #pragma unroll
        for (int j = (1 << w) - 1; j >= 0; --j) {
            float v = base[j];
            base[2*j + 1] = v * sn[w];
            base[2*j]     = v * cn[w];
        }
    }

    f32x4* relay = smem[wid];
    f32x4* stage = smem[wid];
    half8 BhF[4], BlF[4];

    // relay base -> B-frag order (wave-private slab; same-wave in-order DS).
    auto build_bfrags = [&]() {
        #pragma unroll
        for (int q = 0; q < 8; ++q)
            relay[q * 64 + lane] = *(f32x4*)&base[q * 4];
        #pragma unroll
        for (int tb = 0; tb < 4; ++tb) {
            f32x4 r0 = relay[(kg*2 + 0) * 64 + tb*16 + l15];
            f32x4 r1 = relay[(kg*2 + 1) * 64 + tb*16 + l15];
            float b8[8] = {r0[0], r0[1], r0[2], r0[3], r1[0], r1[1], r1[2], r1[3]};
            half8 h, lo;
            #pragma unroll
            for (int e = 0; e < 8; ++e) {
                _Float16 hh = (_Float16)b8[e];
                h[e]  = hh;
                lo[e] = (_Float16)(b8[e] - (float)hh);
            }
            BhF[tb] = h; BlF[tb] = lo;
        }
    };

    if (!bwave) {
        build_bfrags();          // non-B waves progress while the sim runs
    } else {
        // ADJOINT basis sim -> M rows (math verified R12-R15):
        // row r of M = U'^T e_r; loop l=5..0 apply RY(-theta), sign after
        // each layer except l=0. lane -> (g=lane>>4, r=lane&15).
        const int g = lane >> 4;
        const int r = lane & 15;
        float st[DIM];
        #pragma unroll
        for (int i = 0; i < DIM; ++i) st[i] = (i == r) ? 1.0f : 0.0f;
        #pragma unroll
        for (int l = NL - 1; l >= 0; --l) {
            #pragma unroll
            for (int w = 0; w < NQ; ++w) {
                float h = qp[g*(NL*NQ) + l*NQ + w] * RV;
                float c = __builtin_amdgcn_cosf(h);
                float s = __builtin_amdgcn_sinf(h);
                const int bit = 4 - w, str = 1 << bit;
                #pragma unroll
                for (int p = 0; p < 16; ++p) {
                    int lo = ((p >> bit) << (bit + 1)) | (p & (str - 1));
                    int hi = lo + str;
                    float a0 = st[lo], a1 = st[hi];
                    st[lo] = c*a0 + s*a1;      // RY(-theta): transpose of fwd
                    st[hi] = c*a1 - s*a0;
                }
            }
            if (l != 0) {
                #pragma unroll
                for (int i = 0; i < DIM; ++i)
                    if (flip_par(i)) st[i] = -st[i];
            }
        }
        // swizzled write: bank (i+lane)&31 over 64 lanes = 2-way (free)
        #pragma unroll
        for (int i = 0; i < DIM; ++i)
            lmMs[(lane << 5) + ((i + lane) & 31)] = st[i];
    }
    __syncthreads();   // lmMs ready; the only barrier in the kernel

    if (bwave) build_bfrags();   // B-wave catches up (wave-private; no sync)

    // ---- A-fragments from lmMs (b32 reads, 2-way max), f16 hi/lo split
    half8 MhA[NG], MlA[NG];
    #pragma unroll
    for (int g = 0; g < NG; ++g) {
        const int row = g * PATCH + l15;
        float m8[8];
        #pragma unroll
        for (int e = 0; e < 8; ++e)
            m8[e] = lmMs[(row << 5) + ((kg*8 + e + row) & 31)];
        half8 h, lo;
        #pragma unroll
        for (int e = 0; e < 8; ++e) {
            _Float16 hh = (_Float16)m8[e];
            h[e]  = hh;
            lo[e] = (_Float16)(m8[e] - (float)hh);
        }
        MhA[g] = h; MlA[g] = lo;
    }

    // ---- main: FULLY UNROLLED tb x g (rule #20: all reg indices static).
    // Per tb: 4 gens x 3 MFMA -> scaled p into swizzled stage -> 4 x 1KB
    // contiguous NONTEMPORAL stores (nt: bypass L2 allocate for write-once).
    f32x4* ob4 = (f32x4*)(out + (size_t)b0 * 64);
    #pragma unroll
    for (int tb = 0; tb < 4; ++tb) {
        #pragma unroll
        for (int g = 0; g < NG; ++g) {
            f32x4 acc = {0.f, 0.f, 0.f, 0.f};
            acc = __builtin_amdgcn_mfma_f32_16x16x32_f16(MhA[g], BhF[tb], acc, 0, 0, 0);
            acc = __builtin_amdgcn_mfma_f32_16x16x32_f16(MlA[g], BhF[tb], acc, 0, 0, 0);
            acc = __builtin_amdgcn_mfma_f32_16x16x32_f16(MhA[g], BlF[tb], acc, 0, 0, 0);
            // D layout (m89-verified): reg r = slot kg*4+r, col l15 = batch.
            float p0 = acc[0]*acc[0], p1 = acc[1]*acc[1];
            float p2 = acc[2]*acc[2], p3 = acc[3]*acc[3];
            float mx = fmaxf(fmaxf(p0, p1), fmaxf(p2, p3));
            mx = fmaxf(mx, __shfl_xor(mx, 16, 64));   // combine the 4 kg lanes
            mx = fmaxf(mx, __shfl_xor(mx, 32, 64));
            float inv = __builtin_amdgcn_rcpf(mx);
            // swizzled slab: [batch l15][f4-slot (g*4+kg) ^ l15]
            f32x4 v = {p0*inv, p1*inv, p2*inv, p3*inv};
            stage[l15 * 16 + ((g*4 + kg) ^ l15)] = v;
        }
        // drain: 4 KB contiguous (batches tb*16..tb*16+15, full 256-B rows)
        #pragma unroll
        for (int j = 0; j < 4; ++j) {
            int f  = lane + 64 * j;      // f4 index within the tb region
            int br = f >> 4;             // local batch 0..15
            int sl = f & 15;             // f4 slot within the row
            f32x4 v = stage[br * 16 + (sl ^ br)];
            __builtin_nontemporal_store(v, &ob4[tb * 256 + f]);
        }
    }
}

extern "C" void kernel_launch(void* const* d_in, const int* in_sizes, int n_in,
                              void* d_out, int out_size, void* d_ws, size_t ws_size,
                              hipStream_t stream) {
    const float* x  = (const float*)d_in[0];
    const float* qp = (const float*)d_in[1];
    float* out = (float*)d_out;
    const int B = in_sizes[0] / NQ;
    qgen14<<<B / 256, 256, 0, stream>>>(x, qp, out);
}

// Round 17
// 22.461 us; speedup vs baseline: 1.1092x; 1.0909x over previous
//
#include <hip/hip_runtime.h>

#define NQ 5
#define NL 6
#define NG 4
#define DIM 32
#define PATCH 16
#define CHUNKS 2

typedef _Float16 half8 __attribute__((ext_vector_type(8)));
typedef float f32x4 __attribute__((ext_vector_type(4)));

// CZ-chain sign: flip amplitude i iff # adjacent set-bit pairs is odd.
__device__ __forceinline__ int flip_par(int i) {
    int p = i & (i >> 1) & 0xF;
    p ^= p >> 2; p ^= p >> 1;
    return p & 1;
}

// R17 = R14 with CHUNKING: 512 blocks x 2 chunks of 256 batches.
//  * sim + A-frag build run ONCE per block (2x amortization);
//  * chunk-1 prologue (x-load/trig/base/relay/B-frags) issues after chunk-0's
//    drain stores -> hides under the store drain (fire-and-forget writes);
//  * both chunks fully unrolled: every register-array index compile-time
//    (rule #20). Main loop / staging / drain byte-identical to R14/R16 pass.
// bwave = (blockIdx>>7)&3: co-resident pair (b, b+256) -> SIMDs differing
// by 2, so the two sims on a CU land on different SIMDs.
__global__ __launch_bounds__(256, 4) void qgen15(
        const float* __restrict__ x, const float* __restrict__ qp,
        float* __restrict__ out) {
    __shared__ __align__(16) f32x4 smem[4][512];   // 32 KB relay/stage
    __shared__ float lmMs[64 * DIM];               // 8 KB dedicated M

    const int t = threadIdx.x;
    const int wid = t >> 6, lane = t & 63;
    const int l15 = lane & 15, kg = lane >> 4;
    const bool bwave = (wid == ((blockIdx.x >> 7) & 3));
    const float RV = 0.07957747154594767f; // 0.5/(2*pi): v_sin/v_cos take revolutions

    f32x4* relay = smem[wid];
    f32x4* stage = smem[wid];

    float base[DIM];
    half8 BhF[4], BlF[4];

    // x -> trig -> product state for chunk c (batch = blk*512 + c*256 + wid*64 + lane)
    auto load_base = [&](int c) {
        const float* xp = x + ((size_t)blockIdx.x * 512 + c * 256 + wid * 64 + lane) * NQ;
        float cn[NQ], sn[NQ];
        #pragma unroll
        for (int w = 0; w < NQ; ++w) {
            float h = xp[w] * RV;
            cn[w] = __builtin_amdgcn_cosf(h);
            sn[w] = __builtin_amdgcn_sinf(h);
        }
        base[0] = cn[0]; base[1] = sn[0];
        #pragma unroll
        for (int w = 1; w < NQ; ++w) {
            #pragma unroll
            for (int j = (1 << w) - 1; j >= 0; --j) {
                float v = base[j];
                base[2*j + 1] = v * sn[w];
                base[2*j]     = v * cn[w];
            }
        }
    };

    // relay base -> B-frag order (wave-private slab; same-wave in-order DS)
    auto build_bfrags = [&]() {
        #pragma unroll
        for (int q = 0; q < 8; ++q)
            relay[q * 64 + lane] = *(f32x4*)&base[q * 4];
        #pragma unroll
        for (int tb = 0; tb < 4; ++tb) {
            f32x4 r0 = relay[(kg*2 + 0) * 64 + tb*16 + l15];
            f32x4 r1 = relay[(kg*2 + 1) * 64 + tb*16 + l15];
            float b8[8] = {r0[0], r0[1], r0[2], r0[3], r1[0], r1[1], r1[2], r1[3]};
            half8 h, lo;
            #pragma unroll
            for (int e = 0; e < 8; ++e) {
                _Float16 hh = (_Float16)b8[e];
                h[e]  = hh;
                lo[e] = (_Float16)(b8[e] - (float)hh);
            }
            BhF[tb] = h; BlF[tb] = lo;
        }
    };

    if (!bwave) {
        load_base(0);
        build_bfrags();          // non-B waves progress while the sim runs
    } else {
        // ADJOINT basis sim -> M rows (math verified R12-R16):
        // row r of M = U'^T e_r; loop l=5..0 apply RY(-theta), sign after
        // each layer except l=0. lane -> (g=lane>>4, r=lane&15).
        const int g = lane >> 4;
        const int r = lane & 15;
        float st[DIM];
        #pragma unroll
        for (int i = 0; i < DIM; ++i) st[i] = (i == r) ? 1.0f : 0.0f;
        #pragma unroll
        for (int l = NL - 1; l >= 0; --l) {
            #pragma unroll
            for (int w = 0; w < NQ; ++w) {
                float h = qp[g*(NL*NQ) + l*NQ + w] * RV;
                float c = __builtin_amdgcn_cosf(h);
                float s = __builtin_amdgcn_sinf(h);
                const int bit = 4 - w, str = 1 << bit;
                #pragma unroll
                for (int p = 0; p < 16; ++p) {
                    int lo = ((p >> bit) << (bit + 1)) | (p & (str - 1));
                    int hi = lo + str;
                    float a0 = st[lo], a1 = st[hi];
                    st[lo] = c*a0 + s*a1;      // RY(-theta): transpose of fwd
                    st[hi] = c*a1 - s*a0;
                }
            }
            if (l != 0) {
                #pragma unroll
                for (int i = 0; i < DIM; ++i)
                    if (flip_par(i)) st[i] = -st[i];
            }
        }
        // swizzled write: bank (i+lane)&31 over 64 lanes = 2-way (free)
        #pragma unroll
        for (int i = 0; i < DIM; ++i)
            lmMs[(lane << 5) + ((i + lane) & 31)] = st[i];
    }
    __syncthreads();   // lmMs ready; the only barrier in the kernel

    // ---- A-fragments from lmMs, ONCE per block (b32 reads, 2-way max)
    half8 MhA[NG], MlA[NG];
    #pragma unroll
    for (int g = 0; g < NG; ++g) {
        const int row = g * PATCH + l15;
        float m8[8];
        #pragma unroll
        for (int e = 0; e < 8; ++e)
            m8[e] = lmMs[(row << 5) + ((kg*8 + e + row) & 31)];
        half8 h, lo;
        #pragma unroll
        for (int e = 0; e < 8; ++e) {
            _Float16 hh = (_Float16)m8[e];
            h[e]  = hh;
            lo[e] = (_Float16)(m8[e] - (float)hh);
        }
        MhA[g] = h; MlA[g] = lo;
    }

    if (bwave) { load_base(0); build_bfrags(); }   // B-wave catches up

    // ---- chunk loop, FULLY UNROLLED (all register indices compile-time).
    // Per chunk: 4 tb x 4 g x 3 MFMA -> swizzled stage -> 4x1KB contiguous
    // stores; then next chunk's prologue issues (hides under store drain).
    #pragma unroll
    for (int c = 0; c < CHUNKS; ++c) {
        f32x4* ob4 = (f32x4*)(out +
            ((size_t)blockIdx.x * 512 + c * 256 + wid * 64) * 64);
        #pragma unroll
        for (int tb = 0; tb < 4; ++tb) {
            #pragma unroll
            for (int g = 0; g < NG; ++g) {
                f32x4 acc = {0.f, 0.f, 0.f, 0.f};
                acc = __builtin_amdgcn_mfma_f32_16x16x32_f16(MhA[g], BhF[tb], acc, 0, 0, 0);
                acc = __builtin_amdgcn_mfma_f32_16x16x32_f16(MlA[g], BhF[tb], acc, 0, 0, 0);
                acc = __builtin_amdgcn_mfma_f32_16x16x32_f16(MhA[g], BlF[tb], acc, 0, 0, 0);
                // D layout (m89-verified): reg r = slot kg*4+r, col l15 = batch.
                float p0 = acc[0]*acc[0], p1 = acc[1]*acc[1];
                float p2 = acc[2]*acc[2], p3 = acc[3]*acc[3];
                float mx = fmaxf(fmaxf(p0, p1), fmaxf(p2, p3));
                mx = fmaxf(mx, __shfl_xor(mx, 16, 64));   // combine the 4 kg lanes
                mx = fmaxf(mx, __shfl_xor(mx, 32, 64));
                float inv = __builtin_amdgcn_rcpf(mx);
                // swizzled slab: [batch l15][f4-slot (g*4+kg) ^ l15]
                f32x4 v = {p0*inv, p1*inv, p2*inv, p3*inv};
                stage[l15 * 16 + ((g*4 + kg) ^ l15)] = v;
            }
            // drain: 4 KB contiguous (full 256-B rows); same-wave in-order DS
            #pragma unroll
            for (int j = 0; j < 4; ++j) {
                int f  = lane + 64 * j;      // f4 index within the tb region
                int br = f >> 4;             // local batch 0..15
                int sl = f & 15;             // f4 slot within the row
                ob4[tb * 256 + f] = stage[br * 16 + (sl ^ br)];
            }
        }
        if (c + 1 < CHUNKS) {
            load_base(c + 1);    // issues while chunk-c stores drain
            build_bfrags();
        }
    }
}

extern "C" void kernel_launch(void* const* d_in, const int* in_sizes, int n_in,
                              void* d_out, int out_size, void* d_ws, size_t ws_size,
                              hipStream_t stream) {
    const float* x  = (const float*)d_in[0];
    const float* qp = (const float*)d_in[1];
    float* out = (float*)d_out;
    const int B = in_sizes[0] / NQ;          // 262144
    qgen15<<<B / 512, 256, 0, stream>>>(x, qp, out);
}